// Round 2
// baseline (649.746 us; speedup 1.0000x reference)
//
#include <hip/hip_runtime.h>
#include <math.h>

#define V 100000
#define D 128
#define A 64
#define LVLS 3
#define NN 20000
#define KK 16
#define RPW 16   // rows per wave in proj

// proj[dst] = W[src] @ Wsub (128x64) + bias
// src = idx ? idx[j] : j ; dst = dst_from_idx ? src : j
// 16 rows per wave: weight LDS reads amortized 16x -> FMA-bound.
__global__ __launch_bounds__(256)
void proj_kernel(const float* __restrict__ W, const float* __restrict__ Wsub,
                 const float* __restrict__ bias, const int* __restrict__ idx,
                 int dst_from_idx, int nrows, float* __restrict__ outp) {
    __shared__ float sW[D * A];   // 32 KB
    for (int i = threadIdx.x; i < D * A; i += 256) sW[i] = Wsub[i];
    __syncthreads();
    int lane = threadIdx.x & 63, wave = threadIdx.x >> 6;
    float b = bias ? bias[lane] : 0.f;
    int j0 = blockIdx.x * (4 * RPW) + wave * RPW;

    const float* rp[RPW];
    int dst[RPW];
    float acc[RPW];
#pragma unroll
    for (int r = 0; r < RPW; ++r) {
        int j = j0 + r; if (j > nrows - 1) j = nrows - 1;   // clamp; store guarded below
        int src = idx ? idx[j] : j;
        dst[r] = dst_from_idx ? src : j;
        rp[r] = W + (size_t)src * D;
        acc[r] = b;
    }
    for (int d = 0; d < D; d += 4) {
        float w0 = sW[(d + 0) * A + lane];
        float w1 = sW[(d + 1) * A + lane];
        float w2 = sW[(d + 2) * A + lane];
        float w3 = sW[(d + 3) * A + lane];
#pragma unroll
        for (int r = 0; r < RPW; ++r) {
            float4 rv = *(const float4*)(rp[r] + d);   // wave-uniform broadcast load
            acc[r] += rv.x * w0 + rv.y * w1 + rv.z * w2 + rv.w * w3;
        }
    }
#pragma unroll
    for (int r = 0; r < RPW; ++r)
        if (j0 + r < nrows) outp[(size_t)dst[r] * A + lane] = acc[r];
}

// One WAVE per node (4 nodes/block), fully wave-synchronous, no LDS/barriers.
__global__ __launch_bounds__(256)
void attn_kernel(const float* __restrict__ Wc, const float* __restrict__ proj,
                 const float* __restrict__ nodeproj, const int* __restrict__ neigh,
                 const float* __restrict__ maskp, const float* __restrict__ weightp,
                 const float* __restrict__ v_att, float* __restrict__ tmp) {
    int lane = threadIdx.x & 63;
    int n = blockIdx.x * 4 + (threadIdx.x >> 6);
    int k16 = lane & 15;

    int   nbv = neigh[n * KK + k16];     // lanes 0..63: 4 replicated copies of the 16 ids
    float wv  = weightp[n * KK + k16];
    float mk  = maskp[n * KK + k16];
    float np  = nodeproj[(size_t)n * A + lane];
    float va  = v_att[lane];

    // Phase 1: pre[k] = v . leaky(np + proj[nb_k]), lane k16==k keeps it
    float pre = 0.f;
#pragma unroll
    for (int k = 0; k < KK; ++k) {
        int nb = __shfl(nbv, k);
        float x = np + proj[(size_t)nb * A + lane];
        x = x > 0.f ? x : 0.01f * x;
        float p = x * va;
#pragma unroll
        for (int off = 32; off >= 1; off >>= 1) p += __shfl_xor(p, off);
        pre = (k16 == k) ? p : pre;
    }
    pre += mk;

    // Double softmax over the 16-lane groups (all 4 groups identical)
    float mp = pre, mw = wv;
#pragma unroll
    for (int off = 8; off >= 1; off >>= 1) {
        mp = fmaxf(mp, __shfl_xor(mp, off));
        mw = fmaxf(mw, __shfl_xor(mw, off));
    }
    float ep = __expf(pre - mp), ew = __expf(wv - mw);
    float sp = ep, sw = ew;
#pragma unroll
    for (int off = 8; off >= 1; off >>= 1) {
        sp += __shfl_xor(sp, off);
        sw += __shfl_xor(sw, off);
    }
    float att = (ep / sp) * (ew / sw);

    // Phase 2: out[d] = sum_k att_k * Wc[nb_k][d]; lane covers d = 2*lane, 2*lane+1
    float ax = 0.f, ay = 0.f;
#pragma unroll
    for (int k = 0; k < KK; ++k) {
        int nb   = __shfl(nbv, k);
        float ak = __shfl(att, k);
        float2 e = *(const float2*)&Wc[(size_t)nb * D + 2 * lane];
        ax += e.x * ak; ay += e.y * ak;
    }
    float2 o; o.x = ax; o.y = ay;
    *(float2*)&tmp[(size_t)n * D + 2 * lane] = o;
}

__global__ void amax_kernel(const int* __restrict__ nodes_l, int* __restrict__ claim, int n) {
    int i = blockIdx.x * 256 + threadIdx.x;
    if (i < n) atomicMax(&claim[nodes_l[i]], i);
}

// last-occurrence-wins scatter (matches numpy fancy-assign semantics)
__global__ void scatter_kernel(const int* __restrict__ nodes_l, const int* __restrict__ claim,
                               const float* __restrict__ tmp, float* __restrict__ out, int n) {
    int tid = blockIdx.x * 256 + threadIdx.x;
    int nn = tid >> 7, d = tid & 127;
    if (nn < n) {
        int v = nodes_l[nn];
        if (claim[v] == nn) out[(size_t)v * D + d] = tmp[(size_t)nn * D + d];
    }
}

extern "C" void kernel_launch(void* const* d_in, const int* in_sizes, int n_in,
                              void* d_out, int out_size, void* d_ws, size_t ws_size,
                              hipStream_t stream) {
    const float* Leaf    = (const float*)d_in[0];
    const int*   nodes   = (const int*)d_in[1];
    const int*   neigh   = (const int*)d_in[2];
    const float* masks   = (const float*)d_in[3];
    const float* weights = (const float*)d_in[4];
    const float* Watt    = (const float*)d_in[5];
    const float* batt    = (const float*)d_in[6];
    const float* vatt    = (const float*)d_in[7];
    float* out = (float*)d_out;

    char* ws = (char*)d_ws;
    float* proj     = (float*)ws;                                   // V*A
    float* nodeproj = (float*)(ws + (size_t)V * A * 4);             // L*N*A
    float* tmp      = (float*)(ws + (size_t)V * A * 4 + (size_t)LVLS * NN * A * 4);  // N*D
    int*   claim    = (int*)(ws + (size_t)V * A * 4 + (size_t)LVLS * NN * A * 4
                                + (size_t)NN * D * 4);              // V ints

    hipMemcpyAsync(out, Leaf, (size_t)V * D * sizeof(float), hipMemcpyDeviceToDevice, stream);
    // node-half projection for all levels at once (uses ORIGINAL Leaf_emb)
    proj_kernel<<<(LVLS * NN + 4 * RPW - 1) / (4 * RPW), 256, 0, stream>>>(
        Leaf, Watt, batt, nodes, 0, LVLS * NN, nodeproj);
    // neighbor-half projection for all V rows of current W_tmp
    proj_kernel<<<(V + 4 * RPW - 1) / (4 * RPW), 256, 0, stream>>>(
        out, Watt + D * A, nullptr, nullptr, 0, V, proj);

    for (int l = 0; l < LVLS; ++l) {
        const int* nodes_l = nodes + l * NN;
        attn_kernel<<<NN / 4, 256, 0, stream>>>(out, proj, nodeproj + (size_t)l * NN * A,
                                                neigh + (size_t)l * NN * KK,
                                                masks + (size_t)l * NN * KK,
                                                weights + (size_t)l * NN * KK, vatt, tmp);
        hipMemsetAsync(claim, 0xFF, (size_t)V * sizeof(int), stream);   // -1
        amax_kernel<<<(NN + 255) / 256, 256, 0, stream>>>(nodes_l, claim, NN);
        scatter_kernel<<<(NN * D + 255) / 256, 256, 0, stream>>>(nodes_l, claim, tmp, out, NN);
        if (l + 1 < LVLS)  // refresh proj only for rows just rewritten
            proj_kernel<<<(NN + 4 * RPW - 1) / (4 * RPW), 256, 0, stream>>>(
                out, Watt + D * A, nullptr, nodes_l, 1, NN, proj);
    }
}

// Round 3
// 455.948 us; speedup vs baseline: 1.4250x; 1.4250x over previous
//
#include <hip/hip_runtime.h>
#include <math.h>

#define V 100000
#define D 128
#define A 64
#define LVLS 3
#define NN 20000
#define KK 16

// out[dst] = W[src] @ Wmat(128x64) + bias
// Weights-stationary: W[d][lane] in 128 VGPRs; A rows staged per-wave in LDS,
// read back as wave-uniform ds_read_b128 broadcasts. One wave = 16-row tiles,
// grid-strided. No __syncthreads (wave-private LDS regions).
__global__ __launch_bounds__(256, 2)
void proj_kernel(const float* __restrict__ Wsrc, const float* __restrict__ Wmat,
                 const float* __restrict__ bias, const int* __restrict__ idx,
                 int dst_from_idx, int nrows, float* __restrict__ outp) {
    __shared__ float As[4 * 16 * D];   // 32 KB, 8 KB per wave
    int lane = threadIdx.x & 63, wave = threadIdx.x >> 6;
    float* Aw = As + wave * 16 * D;

    float w[D];
#pragma unroll
    for (int d = 0; d < D; ++d) w[d] = Wmat[d * A + lane];
    float b = bias ? bias[lane] : 0.f;

    int ntiles = (nrows + 15) >> 4;
    int stride = gridDim.x * 4;
    for (int t = blockIdx.x * 4 + wave; t < ntiles; t += stride) {
        int r0 = t << 4;
        int lh = lane >> 5;          // row within pair
        int lc = (lane & 31) << 2;   // float offset in row
#pragma unroll
        for (int i = 0; i < 8; ++i) {
            int r = r0 + 2 * i + lh;
            int rr = r < nrows ? r : nrows - 1;
            int src = idx ? idx[rr] : rr;
            float4 v = *(const float4*)(Wsrc + (size_t)src * D + lc);
            *(float4*)(Aw + (2 * i + lh) * D + lc) = v;
        }
        asm volatile("s_waitcnt lgkmcnt(0)" ::: "memory");  // staging visible (in-wave)

        for (int r = 0; r < 16; ++r) {
            const float* ar = Aw + r * D;
            float a0 = b, a1 = 0.f, a2 = 0.f, a3 = 0.f;
#pragma unroll
            for (int dc = 0; dc < D; dc += 16) {
                float4 x0 = *(const float4*)(ar + dc);
                float4 x1 = *(const float4*)(ar + dc + 4);
                float4 x2 = *(const float4*)(ar + dc + 8);
                float4 x3 = *(const float4*)(ar + dc + 12);
                a0 = fmaf(x0.x, w[dc + 0], a0);  a0 = fmaf(x0.y, w[dc + 1], a0);
                a0 = fmaf(x0.z, w[dc + 2], a0);  a0 = fmaf(x0.w, w[dc + 3], a0);
                a1 = fmaf(x1.x, w[dc + 4], a1);  a1 = fmaf(x1.y, w[dc + 5], a1);
                a1 = fmaf(x1.z, w[dc + 6], a1);  a1 = fmaf(x1.w, w[dc + 7], a1);
                a2 = fmaf(x2.x, w[dc + 8], a2);  a2 = fmaf(x2.y, w[dc + 9], a2);
                a2 = fmaf(x2.z, w[dc + 10], a2); a2 = fmaf(x2.w, w[dc + 11], a2);
                a3 = fmaf(x3.x, w[dc + 12], a3); a3 = fmaf(x3.y, w[dc + 13], a3);
                a3 = fmaf(x3.z, w[dc + 14], a3); a3 = fmaf(x3.w, w[dc + 15], a3);
            }
            int rr = r0 + r;
            if (rr < nrows) {
                int src = idx ? idx[rr] : rr;
                int dst = dst_from_idx ? src : rr;
                outp[(size_t)dst * A + lane] = (a0 + a1) + (a2 + a3);
            }
        }
    }
}

// One wave per node. Phase 1: lane (k16 = lane&15, q = lane>>4) computes the
// q-th 16-dim partial of pre[k]; 2 shuffles reduce over q. 16-group softmax
// butterflies. Phase 2: per-lane float2 over D with shfl-broadcast att/nb.
__global__ __launch_bounds__(256)
void attn_kernel(const float* __restrict__ Wc, const float* __restrict__ proj,
                 const float* __restrict__ nodeproj, const int* __restrict__ neigh,
                 const float* __restrict__ maskp, const float* __restrict__ weightp,
                 const float* __restrict__ v_att, float* __restrict__ tmp) {
    int lane = threadIdx.x & 63;
    int n = blockIdx.x * 4 + (threadIdx.x >> 6);
    int k16 = lane & 15, q = lane >> 4;

    int   nbk = neigh[n * KK + k16];
    float wv  = weightp[n * KK + k16];
    float mk  = maskp[n * KK + k16];

    const float* npr = nodeproj + (size_t)n * A + q * 16;
    const float* var = v_att + q * 16;
    const float* pr  = proj + (size_t)nbk * A + q * 16;

    float part = 0.f;
#pragma unroll
    for (int j = 0; j < 16; j += 4) {
        float4 npv = *(const float4*)(npr + j);
        float4 vav = *(const float4*)(var + j);
        float4 pv  = *(const float4*)(pr + j);
        float x;
        x = npv.x + pv.x; x = fmaxf(x, 0.01f * x); part = fmaf(x, vav.x, part);
        x = npv.y + pv.y; x = fmaxf(x, 0.01f * x); part = fmaf(x, vav.y, part);
        x = npv.z + pv.z; x = fmaxf(x, 0.01f * x); part = fmaf(x, vav.z, part);
        x = npv.w + pv.w; x = fmaxf(x, 0.01f * x); part = fmaf(x, vav.w, part);
    }
    part += __shfl_xor(part, 16);
    part += __shfl_xor(part, 32);
    float pre = part + mk;

    float mp = pre, mw = wv;
#pragma unroll
    for (int off = 8; off >= 1; off >>= 1) {
        mp = fmaxf(mp, __shfl_xor(mp, off));
        mw = fmaxf(mw, __shfl_xor(mw, off));
    }
    float ep = __expf(pre - mp), ew = __expf(wv - mw);
    float sp = ep, sw = ew;
#pragma unroll
    for (int off = 8; off >= 1; off >>= 1) {
        sp += __shfl_xor(sp, off);
        sw += __shfl_xor(sw, off);
    }
    float att = (ep / sp) * (ew / sw);

    float ax = 0.f, ay = 0.f;
#pragma unroll
    for (int k = 0; k < KK; ++k) {
        int nb   = __shfl(nbk, k);
        float ak = __shfl(att, k);
        float2 e = *(const float2*)&Wc[(size_t)nb * D + 2 * lane];
        ax = fmaf(e.x, ak, ax); ay = fmaf(e.y, ak, ay);
    }
    float2 o; o.x = ax; o.y = ay;
    *(float2*)&tmp[(size_t)n * D + 2 * lane] = o;
}

__global__ void amax_kernel(const int* __restrict__ nodes_l, int* __restrict__ claim, int n) {
    int i = blockIdx.x * 256 + threadIdx.x;
    if (i < n) atomicMax(&claim[nodes_l[i]], i);
}

// last-occurrence-wins scatter (matches numpy fancy-assign semantics)
__global__ void scatter_kernel(const int* __restrict__ nodes_l, const int* __restrict__ claim,
                               const float* __restrict__ tmp, float* __restrict__ out, int n) {
    int tid = blockIdx.x * 256 + threadIdx.x;
    int nn = tid >> 7, d = tid & 127;
    if (nn < n) {
        int v = nodes_l[nn];
        if (claim[v] == nn) out[(size_t)v * D + d] = tmp[(size_t)nn * D + d];
    }
}

extern "C" void kernel_launch(void* const* d_in, const int* in_sizes, int n_in,
                              void* d_out, int out_size, void* d_ws, size_t ws_size,
                              hipStream_t stream) {
    const float* Leaf    = (const float*)d_in[0];
    const int*   nodes   = (const int*)d_in[1];
    const int*   neigh   = (const int*)d_in[2];
    const float* masks   = (const float*)d_in[3];
    const float* weights = (const float*)d_in[4];
    const float* Watt    = (const float*)d_in[5];
    const float* batt    = (const float*)d_in[6];
    const float* vatt    = (const float*)d_in[7];
    float* out = (float*)d_out;

    char* ws = (char*)d_ws;
    float* proj     = (float*)ws;                                   // V*A
    float* nodeproj = (float*)(ws + (size_t)V * A * 4);             // L*N*A
    float* tmp      = (float*)(ws + (size_t)V * A * 4 + (size_t)LVLS * NN * A * 4);  // N*D
    int*   claim    = (int*)(ws + (size_t)V * A * 4 + (size_t)LVLS * NN * A * 4
                                + (size_t)NN * D * 4);              // V ints

    hipMemcpyAsync(out, Leaf, (size_t)V * D * sizeof(float), hipMemcpyDeviceToDevice, stream);

    // node-half projection for all levels (ORIGINAL Leaf_emb rows)
    {
        int ntiles = (LVLS * NN + 15) >> 4;
        int blocks = (ntiles + 3) / 4; if (blocks > 512) blocks = 512;
        proj_kernel<<<blocks, 256, 0, stream>>>(Leaf, Watt, batt, nodes, 0, LVLS * NN, nodeproj);
    }
    // neighbor-half projection for all V rows of current W_tmp
    {
        int ntiles = (V + 15) >> 4;
        int blocks = (ntiles + 3) / 4; if (blocks > 512) blocks = 512;
        proj_kernel<<<blocks, 256, 0, stream>>>(out, Watt + D * A, nullptr, nullptr, 0, V, proj);
    }

    for (int l = 0; l < LVLS; ++l) {
        const int* nodes_l = nodes + l * NN;
        attn_kernel<<<NN / 4, 256, 0, stream>>>(out, proj, nodeproj + (size_t)l * NN * A,
                                                neigh + (size_t)l * NN * KK,
                                                masks + (size_t)l * NN * KK,
                                                weights + (size_t)l * NN * KK, vatt, tmp);
        hipMemsetAsync(claim, 0xFF, (size_t)V * sizeof(int), stream);   // -1
        amax_kernel<<<(NN + 255) / 256, 256, 0, stream>>>(nodes_l, claim, NN);
        scatter_kernel<<<(NN * D + 255) / 256, 256, 0, stream>>>(nodes_l, claim, tmp, out, NN);
        if (l + 1 < LVLS) {  // refresh proj only for rows just rewritten
            int ntiles = (NN + 15) >> 4;
            int blocks = (ntiles + 3) / 4; if (blocks > 512) blocks = 512;
            proj_kernel<<<blocks, 256, 0, stream>>>(out, Watt + D * A, nullptr, nodes_l, 1, NN, proj);
        }
    }
}